// Round 5
// baseline (646.338 us; speedup 1.0000x reference)
//
#include <hip/hip_runtime.h>

// ---------------------------------------------------------------------------
// GCN 3-layer forward on MI355X — Round 9: wide (16B/lane) gather.
// R8 counters: agg_gather<256> = 117.5us, hbm 3.9TB/s miss-path, VALUBusy 26%,
// occupancy 75% -- no pipe saturated => bound by bytes-in-flight, which is
// capped by the outstanding-VMEM-INSTRUCTION budget x 512B/instr (one 8B/lane
// wave-load per edge). Fix: uint4 (8 fp16) loads, L = D/8 lanes per node ->
// one wave instruction covers TWO nodes' neighbor rows (1KB/instr): instrs
// per edge halve, bytes-in-flight double. Broadcast via __shfl width L.
// Side: count_deg / fill_csr vectorized x4 (int4 col/seq/row).
// GEMM (fp16 MFMA + XCD pairing, R8), scan (R6), folded norm (R8) unchanged.
// ---------------------------------------------------------------------------

constexpr int DIN = 128;
constexpr int DH  = 256;

typedef _Float16 f16x8 __attribute__((ext_vector_type(8)));
typedef float    f32x4 __attribute__((ext_vector_type(4)));

__device__ __forceinline__ float h2f(unsigned short u) {
    _Float16 h;
    __builtin_memcpy(&h, &u, 2);
    return (float)h;
}
__device__ __forceinline__ unsigned short f2h(float f) {
    _Float16 h = (_Float16)f;
    unsigned short u;
    __builtin_memcpy(&u, &h, 2);
    return u;
}

union U4H8 { uint4 u; _Float16 h[8]; };

__global__ void zero_int_kernel(int* __restrict__ p, int n) {
    int i = blockIdx.x * blockDim.x + threadIdx.x;
    if (i < n) p[i] = 0;
}

// Degree count x4; atomic return value = within-node slot -> seq[e].
__global__ void count_deg_kernel(const int* __restrict__ col, int E,
                                 int* __restrict__ deg, int* __restrict__ seq) {
    int i = blockIdx.x * blockDim.x + threadIdx.x;
    int base = i * 4;
    if (base >= E) return;
    if (base + 4 <= E && (((size_t)col & 15) == 0)) {
        int4 c = *(const int4*)(col + base);
        int4 s;
        s.x = atomicAdd(&deg[c.x], 1);
        s.y = atomicAdd(&deg[c.y], 1);
        s.z = atomicAdd(&deg[c.z], 1);
        s.w = atomicAdd(&deg[c.w], 1);
        *(int4*)(seq + base) = s;
    } else {
        for (int e = base; e < E && e < base + 4; ++e)
            seq[e] = atomicAdd(&deg[col[e]], 1);
    }
}

// ---- 3-phase multi-block exclusive scan over deg[0..N) -> rowptr[0..N] ----
__global__ __launch_bounds__(256) void scan_p1_kernel(const int* __restrict__ deg,
                                                      int* __restrict__ bsum, int N) {
    int t = threadIdx.x;
    int base = blockIdx.x * 1024 + t * 4;
    int s = 0;
    #pragma unroll
    for (int k = 0; k < 4; k++) { int i = base + k; if (i < N) s += deg[i]; }
    __shared__ int red[256];
    red[t] = s;
    __syncthreads();
    for (int off = 128; off > 0; off >>= 1) {
        if (t < off) red[t] += red[t + off];
        __syncthreads();
    }
    if (t == 0) bsum[blockIdx.x] = red[0];
}

__global__ __launch_bounds__(1024) void scan_p2_kernel(int* __restrict__ bsum, int nb) {
    __shared__ int sums[1024];
    int t = threadIdx.x;
    int chunk = (nb + 1023) / 1024;
    int s0 = t * chunk, s1 = min(nb, s0 + chunk);
    int local = 0;
    for (int i = s0; i < s1; i++) local += bsum[i];
    sums[t] = local;
    __syncthreads();
    for (int off = 1; off < 1024; off <<= 1) {
        int v = (t >= off) ? sums[t - off] : 0;
        __syncthreads();
        sums[t] += v;
        __syncthreads();
    }
    int prefix = (t == 0) ? 0 : sums[t - 1];
    for (int i = s0; i < s1; i++) { int v = bsum[i]; bsum[i] = prefix; prefix += v; }
}

// Phase 3: block-local exclusive scan + bsum[b] offset -> rowptr.
// Fused: dinv[i] = 1/sqrt(deg[i]+1).
__global__ __launch_bounds__(256) void scan_p3_kernel(const int* __restrict__ deg,
                                                      const int* __restrict__ bsum,
                                                      int* __restrict__ rowptr,
                                                      float* __restrict__ dinv,
                                                      int N, int E) {
    int t = threadIdx.x;
    int base = blockIdx.x * 1024 + t * 4;
    int v[4];
    int s = 0;
    #pragma unroll
    for (int k = 0; k < 4; k++) {
        int i = base + k;
        v[k] = (i < N) ? deg[i] : 0;
        s += v[k];
    }
    __shared__ int sums[256];
    sums[t] = s;
    __syncthreads();
    for (int off = 1; off < 256; off <<= 1) {
        int u = (t >= off) ? sums[t - off] : 0;
        __syncthreads();
        sums[t] += u;
        __syncthreads();
    }
    int prefix = bsum[blockIdx.x] + ((t == 0) ? 0 : sums[t - 1]);
    #pragma unroll
    for (int k = 0; k < 4; k++) {
        int i = base + k;
        if (i < N) {
            rowptr[i] = prefix;
            dinv[i] = 1.0f / sqrtf((float)(v[k] + 1));
        }
        prefix += v[k];
    }
    if (blockIdx.x == 0 && t == 0) rowptr[N] = E;
}

// Atomic-free CSR fill x4: pos = rowptr[col] + seq.
__global__ void fill_csr_kernel(const int* __restrict__ row, const int* __restrict__ col,
                                const int* __restrict__ seq, const int* __restrict__ rowptr,
                                int* __restrict__ csr_src, int E) {
    int i = blockIdx.x * blockDim.x + threadIdx.x;
    int base = i * 4;
    if (base >= E) return;
    if (base + 4 <= E && (((size_t)col & 15) == 0)) {
        int4 c = *(const int4*)(col + base);
        int4 s = *(const int4*)(seq + base);
        int4 r = *(const int4*)(row + base);
        csr_src[rowptr[c.x] + s.x] = r.x;
        csr_src[rowptr[c.y] + s.y] = r.y;
        csr_src[rowptr[c.z] + s.z] = r.z;
        csr_src[rowptr[c.w] + s.w] = r.w;
    } else {
        for (int e = base; e < E && e < base + 4; ++e)
            csr_src[rowptr[col[e]] + seq[e]] = row[e];
    }
}

// fp32 -> fp16 cast (RNE), 4 elems/thread.
__global__ void cast_f16_kernel(const float4* __restrict__ in, ushort4* __restrict__ out, int n4) {
    int i = blockIdx.x * blockDim.x + threadIdx.x;
    if (i >= n4) return;
    float4 v = in[i];
    ushort4 o;
    o.x = f2h(v.x); o.y = f2h(v.y); o.z = f2h(v.z); o.w = f2h(v.w);
    out[i] = o;
}

// x~ = dinv[row] * x, fp16. Row of elem group i (4 fp32) = i / (DIN/4).
__global__ void cast_f16_scaled_kernel(const float4* __restrict__ in,
                                       const float* __restrict__ dinv,
                                       ushort4* __restrict__ out, int n4) {
    int i = blockIdx.x * blockDim.x + threadIdx.x;
    if (i >= n4) return;
    float s = dinv[i >> 5];                  // DIN/4 = 32 groups per row
    float4 v = in[i];
    ushort4 o;
    o.x = f2h(v.x * s); o.y = f2h(v.y * s); o.z = f2h(v.z * s); o.w = f2h(v.w * s);
    out[i] = o;
}

// Wide gather: L = D/8 lanes per node, 16B (8 fp16) per lane. One wave-load
// instruction covers 64/L nodes' rows (1KB for D=256) -> 2x bytes-in-flight
// at the same outstanding-instruction budget. Unroll x8 for MLP.
// in: PRE-SCALED fp16 rows; out[n] = f2h(dinv[n] * (sum + self)).
template<int D>
__global__ __launch_bounds__(256) void agg_gather_f16_kernel(const int* __restrict__ rowptr,
                                                             const int* __restrict__ csr_src,
                                                             const float* __restrict__ dinv,
                                                             const uint4* __restrict__ in,
                                                             uint4* __restrict__ out, int N) {
    constexpr int L = D / 8;                 // 32 (D=256) or 16 (D=128)
    constexpr int GPB = 256 / L;
    int n = blockIdx.x * GPB + threadIdx.x / L;
    if (n >= N) return;
    int lane = threadIdx.x % L;

    float acc[8];
    {
        U4H8 sv; sv.u = in[(size_t)n * L + lane];
        #pragma unroll
        for (int k = 0; k < 8; k++) acc[k] = (float)sv.h[k];
    }

    int start = rowptr[n], end = rowptr[n + 1];
    for (int j0 = start; j0 < end; j0 += L) {
        int nb = end - j0; if (nb > L) nb = L;
        int src = (lane < nb) ? csr_src[j0 + lane] : 0;

        int t = 0;
        for (; t + 8 <= nb; t += 8) {
            int rr[8];
            #pragma unroll
            for (int u = 0; u < 8; ++u) rr[u] = __shfl(src, t + u, L);
            U4H8 vv[8];
            #pragma unroll
            for (int u = 0; u < 8; ++u) vv[u].u = in[(size_t)rr[u] * L + lane];
            #pragma unroll
            for (int u = 0; u < 8; ++u)
                #pragma unroll
                for (int k = 0; k < 8; k++) acc[k] += (float)vv[u].h[k];
        }
        for (; t < nb; ++t) {
            int r = __shfl(src, t, L);
            U4H8 v; v.u = in[(size_t)r * L + lane];
            #pragma unroll
            for (int k = 0; k < 8; k++) acc[k] += (float)v.h[k];
        }
    }
    float s = dinv[n];
    U4H8 o;
    #pragma unroll
    for (int k = 0; k < 8; k++) o.h[k] = (_Float16)(acc[k] * s);
    out[(size_t)n * L + lane] = o.u;
}

// C[n][m] = sum_k A[n][k]*W[m][k]; A:[N,K] fp16, W:[256,K] fp16 (pre-cast).
// MFMA f16, fp32 accum. 128x128 tile, BK=64, 4 waves (2x2), 64x64 per wave.
// 1D grid, XCD-pairing decode: hw blocks 16g+r and 16g+r+8 (same XCD under
// round-robin) share cx -> second A-tile read hits that XCD's L2.
// SCALE: multiply output row by dinv[row] before fp16 store (h~ = dinv*relu).
template<int K, bool RELU, bool SCALE, typename OT>
__global__ __launch_bounds__(256) void gemm_nt_mfma_kernel(const unsigned short* __restrict__ A,
                                                           const unsigned short* __restrict__ Wh,
                                                           OT* __restrict__ C,
                                                           const float* __restrict__ dinv, int N) {
    __shared__ __align__(16) unsigned short As[128 * 64];
    __shared__ __align__(16) unsigned short Ws[128 * 64];
    int tid  = threadIdx.x;
    int lane = tid & 63;
    int wave = tid >> 6;
    int wr = wave >> 1, wc = wave & 1;       // wave grid 2x2

    // ---- XCD-pairing block decode
    int nwgx = (N + 127) / 128;
    int T = (2 * nwgx) & ~15;
    int b = blockIdx.x;
    int cx, cy;
    if (b < T) { cx = (b >> 4) * 8 + (b & 7); cy = (b >> 3) & 1; }
    else       { int rem = b - T; cx = (T >> 1) + (rem >> 1); cy = rem & 1; }
    int m0 = cx * 128;                       // output rows (nodes)
    int c0 = cy * 128;                       // output cols (0 or 128)

    f32x4 acc[4][4];
    #pragma unroll
    for (int i = 0; i < 4; i++)
        #pragma unroll
        for (int j = 0; j < 4; j++)
            #pragma unroll
            for (int r = 0; r < 4; r++) acc[i][j][r] = 0.0f;

    int srow  = tid >> 3;                    // 0..31: staging row within pass
    int sslot = tid & 7;                     // 16B slot within row (8 slots = 64 fp16)

    for (int k0 = 0; k0 < K; k0 += 64) {
        // ---- stage A[m0..m0+127][k0..k0+63] and W[c0..c0+127][k0..k0+63]
        #pragma unroll
        for (int q = 0; q < 4; ++q) {
            int row = q * 32 + srow;
            int byteoff = row * 128 + ((sslot ^ (row & 7)) << 4);
            int gr = m0 + row;
            if (gr >= N) gr = N - 1;         // clamp: tail rows computed, never stored
            f16x8 va = *(const f16x8*)(A + (size_t)gr * K + k0 + sslot * 8);
            *(f16x8*)((char*)As + byteoff) = va;
            int gw = c0 + row;               // always < 256
            f16x8 vw = *(const f16x8*)(Wh + (size_t)gw * K + k0 + sslot * 8);
            *(f16x8*)((char*)Ws + byteoff) = vw;
        }
        __syncthreads();

        // ---- 2 x K=32 MFMA steps over this BK=64 tile
        #pragma unroll
        for (int kk = 0; kk < 2; ++kk) {
            int slot = kk * 4 + (lane >> 4);
            f16x8 a[4], bfr[4];
            #pragma unroll
            for (int i = 0; i < 4; i++) {
                int row = wr * 64 + i * 16 + (lane & 15);
                a[i] = *(const f16x8*)((const char*)As + row * 128 + ((slot ^ (row & 7)) << 4));
            }
            #pragma unroll
            for (int j = 0; j < 4; j++) {
                int row = wc * 64 + j * 16 + (lane & 15);
                bfr[j] = *(const f16x8*)((const char*)Ws + row * 128 + ((slot ^ (row & 7)) << 4));
            }
            #pragma unroll
            for (int i = 0; i < 4; i++)
                #pragma unroll
                for (int j = 0; j < 4; j++)
                    acc[i][j] = __builtin_amdgcn_mfma_f32_16x16x32_f16(a[i], bfr[j], acc[i][j], 0, 0, 0);
        }
        __syncthreads();
    }

    // ---- epilogue: D lane map (verified m89): col = lane&15, row = (lane>>4)*4 + r
    int r4 = (lane >> 4) * 4;
    int cn = lane & 15;
    #pragma unroll
    for (int i = 0; i < 4; i++) {
        #pragma unroll
        for (int r = 0; r < 4; r++) {
            int g_r = m0 + wr * 64 + i * 16 + r4 + r;
            if (g_r >= N) continue;
            float dv = SCALE ? dinv[g_r] : 1.0f;
            #pragma unroll
            for (int j = 0; j < 4; j++) {
                float v = acc[i][j][r];
                if (RELU) v = fmaxf(v, 0.f);
                if (SCALE) v *= dv;
                int col = c0 + wc * 64 + j * 16 + cn;
                if constexpr (sizeof(OT) == 4) {
                    ((float*)C)[(size_t)g_r * DH + col] = v;
                } else {
                    ((unsigned short*)C)[(size_t)g_r * DH + col] = f2h(v);
                }
            }
        }
    }
}

extern "C" void kernel_launch(void* const* d_in, const int* in_sizes, int n_in,
                              void* d_out, int out_size, void* d_ws, size_t ws_size,
                              hipStream_t stream) {
    const float* x  = (const float*)d_in[0];
    const int*   ei = (const int*)d_in[1];
    const float* W1 = (const float*)d_in[2];
    const float* W2 = (const float*)d_in[3];
    const float* W3 = (const float*)d_in[4];
    float* out = (float*)d_out;

    int N = in_sizes[0] / DIN;
    int E = in_sizes[1] / 2;
    const int* row = ei;         // sources
    const int* col = ei + E;     // targets (aggregation)

    char* ws = (char*)d_ws;
    int*   deg     = (int*)ws;                      // N ints
    float* dinv    = (float*)(ws + 400000);         // N floats
    int*   rowptr  = (int*)(ws + 800000);           // N+1 ints
    int*   csr_src = (int*)(ws + 1200016);          // E ints
    int*   seq     = (int*)(ws + 7600016);          // E ints
    unsigned short* bufA = (unsigned short*)(ws + 14000128);  // N*256 fp16 agg out (A operand)
    unsigned short* w1h  = (unsigned short*)(ws + 65200128);  // 256*128 fp16
    unsigned short* w2h  = (unsigned short*)(ws + 65265664);  // 256*256 fp16
    unsigned short* w3h  = (unsigned short*)(ws + 65396736);  // 256*256 fp16
    int*   bsum    = (int*)(ws + 65527808);         // ~(N/1024)+1 ints, scan block sums

    // fp16 staging for gather inputs lives inside d_out (dead/overwritten):
    // x~ (N*128, 25.6MB) is dead before GEMM1 writes h~ (N*256 fp16, 51.2MB)
    // over it; GEMM3 fully overwrites d_out with the fp32 result.
    unsigned short* hb = (unsigned short*)d_out;

    dim3 b256(256);
    int nb = (N + 1023) / 1024;                     // scan blocks (98 @ N=100K)

    // CSR build: deg+seq -> rowptr (3-phase scan, dinv fused) -> atomic-free fill
    zero_int_kernel<<<dim3((N + 255) / 256), b256, 0, stream>>>(deg, N);
    count_deg_kernel<<<dim3(((E + 3) / 4 + 255) / 256), b256, 0, stream>>>(col, E, deg, seq);
    scan_p1_kernel<<<dim3(nb), b256, 0, stream>>>(deg, bsum, N);
    scan_p2_kernel<<<dim3(1), dim3(1024), 0, stream>>>(bsum, nb);
    scan_p3_kernel<<<dim3(nb), b256, 0, stream>>>(deg, bsum, rowptr, dinv, N, E);
    fill_csr_kernel<<<dim3(((E + 3) / 4 + 255) / 256), b256, 0, stream>>>(
        row, col, seq, rowptr, csr_src, E);

    // Pre-cast weights; x~ = dinv*x (scan_p3 produced dinv before this point)
    cast_f16_scaled_kernel<<<dim3((N * (DIN / 4) + 255) / 256), b256, 0, stream>>>(
        (const float4*)x, dinv, (ushort4*)hb, N * (DIN / 4));
    cast_f16_kernel<<<dim3((DH * DIN / 4 + 255) / 256), b256, 0, stream>>>(
        (const float4*)W1, (ushort4*)w1h, DH * DIN / 4);
    cast_f16_kernel<<<dim3((DH * DH / 4 + 255) / 256), b256, 0, stream>>>(
        (const float4*)W2, (ushort4*)w2h, DH * DH / 4);
    cast_f16_kernel<<<dim3((DH * DH / 4 + 255) / 256), b256, 0, stream>>>(
        (const float4*)W3, (ushort4*)w3h, DH * DH / 4);

    int nwg = 2 * ((N + 127) / 128);

    // ---- Layer 1: s = dinv*(sum x~); h1~ = dinv*f16(relu(s @ W1^T))
    agg_gather_f16_kernel<DIN><<<dim3((N + 15) / 16), b256, 0, stream>>>(
        rowptr, csr_src, dinv, (const uint4*)hb, (uint4*)bufA, N);
    gemm_nt_mfma_kernel<DIN, true, true, unsigned short><<<dim3(nwg), b256, 0, stream>>>(
        bufA, w1h, hb, dinv, N);

    // ---- Layer 2: s = dinv*(sum h1~); h2~ = dinv*f16(relu(s @ W2^T))
    agg_gather_f16_kernel<DH><<<dim3((N + 7) / 8), b256, 0, stream>>>(
        rowptr, csr_src, dinv, (const uint4*)hb, (uint4*)bufA, N);
    gemm_nt_mfma_kernel<DH, true, true, unsigned short><<<dim3(nwg), b256, 0, stream>>>(
        bufA, w2h, hb, dinv, N);

    // ---- Layer 3: s = dinv*(sum h2~); out = s @ W3^T (fp32, full overwrite)
    agg_gather_f16_kernel<DH><<<dim3((N + 7) / 8), b256, 0, stream>>>(
        rowptr, csr_src, dinv, (const uint4*)hb, (uint4*)bufA, N);
    gemm_nt_mfma_kernel<DH, false, false, float><<<dim3(nwg), b256, 0, stream>>>(
        bufA, w3h, out, dinv, N);
}